// Round 14
// baseline (169.221 us; speedup 1.0000x reference)
//
#include <hip/hip_runtime.h>

// MLPNodeLink: out[i,j] = relu(relu(relu([V1_i|V2_j]@W1+b1)@W2+b2)@W3+b3)
// h1[i,j] = relu(A[i] + B[j]), A=V1@W1[:128]+b1, B=V2@W1[128:]
// Round 14: L2-BW attack. BM=128 via 16 waves (1024 thr) of the SAME 64x64
// tile (acc=64) -> W2 L2 traffic halves (2.1GB -> 1.05GB). Wave = (rh, cs):
// rows rh*64+mt*32+cl, cols cs*64+nt*32+cl. K-loop per wave identical to r13
// (bfr 3-slot dist-2 from L2, af dbuf from 128KB sA). 1 block/CU, 4 w/SIMD.

typedef short bf16x8 __attribute__((ext_vector_type(8)));
typedef float f32x16 __attribute__((ext_vector_type(16)));

#define NROW 512
#define FDIM 128
#define HDIM 512

__device__ __forceinline__ unsigned int pk2(float x, float y) {
  unsigned int r;
  asm("v_cvt_pk_bf16_f32 %0, %1, %2" : "=v"(r) : "v"(x), "v"(y));
  return r;
}

// ---- prep_ab: A[i][h] = V1[i]@W1[:128] + b1 ; B[j][h] = V2[j]@W1[128:] ----
__global__ __launch_bounds__(256) void prep_ab(
    const float* __restrict__ V1, const float* __restrict__ V2,
    const float* __restrict__ W1, const float* __restrict__ b1,
    float* __restrict__ Ap, float* __restrict__ Bp) {
  __shared__ float sv[4 * FDIM];
  const int b = blockIdx.x;
  const int t = threadIdx.x;
  const bool isB = b >= 128;
  const int r0 = (b & 127) * 4;
  const float* V = isB ? V2 : V1;
  const float* W = W1 + (isB ? FDIM * HDIM : 0);
  for (int idx = t; idx < 4 * FDIM; idx += 256) sv[idx] = V[r0 * FDIM + idx];
  __syncthreads();
  float s[4][2] = {};
  for (int k = 0; k < FDIM; ++k) {
    const float w0 = W[k * HDIM + t];
    const float w1 = W[k * HDIM + t + 256];
#pragma unroll
    for (int r = 0; r < 4; ++r) {
      const float v = sv[r * FDIM + k];
      s[r][0] += v * w0;
      s[r][1] += v * w1;
    }
  }
  float* O = isB ? Bp : Ap;
  const float bb0 = isB ? 0.f : b1[t];
  const float bb1 = isB ? 0.f : b1[t + 256];
#pragma unroll
  for (int r = 0; r < 4; ++r) {
    O[(r0 + r) * HDIM + t] = s[r][0] + bb0;
    O[(r0 + r) * HDIM + t + 256] = s[r][1] + bb1;
  }
}

// ---- prep_w2: bf16 W2^T as [kc=k/8 (64)][n (512)] 16B chunks ----
__global__ __launch_bounds__(256) void prep_w2(const float* __restrict__ W2,
                                               unsigned short* __restrict__ W2T) {
  const int o = blockIdx.x * 256 + threadIdx.x;  // 128*256 = 32768 chunks
  const int kc = o >> 9;
  const int n = o & 511;
  unsigned int u[4];
#pragma unroll
  for (int e2 = 0; e2 < 4; ++e2)
    u[e2] = pk2(W2[(kc * 8 + 2 * e2) * HDIM + n], W2[(kc * 8 + 2 * e2 + 1) * HDIM + n]);
  *(uint4*)(W2T + (size_t)o * 8) = make_uint4(u[0], u[1], u[2], u[3]);
}

// ---- main: 128 pair-rows x 512 cols per block; 16 waves, each 64x64 tile
// (2x2 frags of 32x32): rh = wave>>3 (row-half), cs = wave&7 (col-slice).
// K pipelined in 32 steps of 16; af dbuf 1-deep, bfr 3-slot distance-2.
__global__ __launch_bounds__(1024, 4) void mlp_main(
    const float* __restrict__ Ap, const float* __restrict__ Bp,
    const unsigned short* __restrict__ W2T, const float* __restrict__ b2,
    const float* __restrict__ W3, const float* __restrict__ b3,
    float* __restrict__ out) {
  extern __shared__ char smem[];
  char* sA = smem;  // 128 rows x 1024B (swizzled); epi reuses first 64KB

  const int tid = threadIdx.x;
  const int wave = tid >> 6;
  const int lane = tid & 63;
  const int cl = lane & 31;   // frag row/col index
  const int hi = lane >> 5;   // k-octet select
  const int r15 = lane & 15;  // = row&15 for all this lane's af rows
  const int rh = wave >> 3;   // row-half 0/1
  const int cs = wave & 7;    // col-slice 0..7

  const int m0 = blockIdx.x * 128;
  const int i = m0 >> 9;
  const int j0 = m0 & 511;

  // ---- fill: h1 tile (128 rows x 512 k) -> sA, 4-bit XOR swizzle ----
  {
    const int c = tid & 63;      // 16B chunk (8 k-elems)
    const int rsub = tid >> 6;   // 0..15
    const float4 a0 = *(const float4*)(Ap + i * HDIM + c * 8);
    const float4 a1 = *(const float4*)(Ap + i * HDIM + c * 8 + 4);
#pragma unroll
    for (int it = 0; it < 8; ++it) {
      const int row = it * 16 + rsub;
      const float4 g0 = *(const float4*)(Bp + (size_t)(j0 + row) * HDIM + c * 8);
      const float4 g1 = *(const float4*)(Bp + (size_t)(j0 + row) * HDIM + c * 8 + 4);
      const uint4 v = make_uint4(
          pk2(fmaxf(a0.x + g0.x, 0.f), fmaxf(a0.y + g0.y, 0.f)),
          pk2(fmaxf(a0.z + g0.z, 0.f), fmaxf(a0.w + g0.w, 0.f)),
          pk2(fmaxf(a1.x + g1.x, 0.f), fmaxf(a1.y + g1.y, 0.f)),
          pk2(fmaxf(a1.z + g1.z, 0.f), fmaxf(a1.w + g1.w, 0.f)));
      *(uint4*)(sA + row * 1024 + ((c ^ (row & 15)) << 4)) = v;
    }
  }

  // hoisted epilogue weights
  float w30[2], w31[2], bb[2];
#pragma unroll
  for (int nt = 0; nt < 2; ++nt) {
    const int n = (cs << 6) + (nt << 5) + cl;
    w30[nt] = W3[2 * n];
    w31[nt] = W3[2 * n + 1];
    bb[nt] = b2[n];
  }
  const float bb3_0 = b3[0], bb3_1 = b3[1];

  __syncthreads();

  // ---- barrier-free pipelined K-loop: 32 steps of K=16 ----
  f32x16 acc[2][2];
#pragma unroll
  for (int mt = 0; mt < 2; ++mt)
#pragma unroll
    for (int nt = 0; nt < 2; ++nt)
#pragma unroll
      for (int q = 0; q < 16; ++q) acc[mt][nt][q] = 0.f;

  const char* abase0 = sA + (rh * 64 + cl) * 1024;  // mt=1 at +32768
  const char* bbase = (const char*)W2T + (((cs << 6) + cl) << 4) + (hi << 13);

  bf16x8 af[2][2], bfr[3][2];
  {
    const int off = (hi ^ r15) << 4;  // s=0
    af[0][0] = *(const bf16x8*)(abase0 + off);
    af[0][1] = *(const bf16x8*)(abase0 + 32768 + off);
#pragma unroll
    for (int q = 0; q < 2; ++q) {  // s=0,1 -> slots 0,1
      const char* bp = bbase + ((size_t)q << 14);
      bfr[q][0] = *(const bf16x8*)(bp);
      bfr[q][1] = *(const bf16x8*)(bp + (1 << 9));
    }
  }
#pragma unroll
  for (int s = 0; s < 32; ++s) {
    const int cur = s & 1;
    const int nxt = cur ^ 1;
    if (s < 30) {
      const char* bp = bbase + ((size_t)(s + 2) << 14);
      bfr[(s + 2) % 3][0] = *(const bf16x8*)(bp);
      bfr[(s + 2) % 3][1] = *(const bf16x8*)(bp + (1 << 9));
    }
    if (s < 31) {
      const int off = ((((s + 1) << 1) | hi) ^ r15) << 4;
      af[nxt][0] = *(const bf16x8*)(abase0 + off);
      af[nxt][1] = *(const bf16x8*)(abase0 + 32768 + off);
    }
    __builtin_amdgcn_s_setprio(1);
#pragma unroll
    for (int nt = 0; nt < 2; ++nt)
#pragma unroll
      for (int mt = 0; mt < 2; ++mt)
        acc[mt][nt] = __builtin_amdgcn_mfma_f32_32x32x16_bf16(af[cur][mt], bfr[s % 3][nt],
                                                              acc[mt][nt], 0, 0, 0);
    __builtin_amdgcn_s_setprio(0);
  }

  __syncthreads();  // sA reads done; buffer reused below

  // ---- epilogue: 4 rounds over (rhr, mt); buffer [16rp][256 slot][16B] ----
  for (int rhr = 0; rhr < 2; ++rhr) {
    for (int mt = 0; mt < 2; ++mt) {
      if (rh == rhr) {
#pragma unroll
        for (int rp = 0; rp < 8; ++rp) {
          const int ra = 2 * rp;
          const float h0a = fmaxf(acc[mt][0][ra] + bb[0], 0.f);
          const float h1a = fmaxf(acc[mt][1][ra] + bb[1], 0.f);
          const float h0b = fmaxf(acc[mt][0][ra + 1] + bb[0], 0.f);
          const float h1b = fmaxf(acc[mt][1][ra + 1] + bb[1], 0.f);
          const float4 v =
              make_float4(h0a * w30[0] + h1a * w30[1], h0a * w31[0] + h1a * w31[1],
                          h0b * w30[0] + h1b * w30[1], h0b * w31[0] + h1b * w31[1]);
          const int rpi = ((ra & 3) + 8 * (ra >> 2) + 4 * hi) >> 1;
          *(float4*)(smem + rpi * 4096 + (((cs << 5) + cl) << 4)) = v;
        }
      }
      __syncthreads();
      if (tid < 256) {
        const int rpi = tid >> 4;  // 0..15
        const int sub = tid & 15;  // 16 threads per rowpair
        float4 s = make_float4(0.f, 0.f, 0.f, 0.f);
#pragma unroll
        for (int k = 0; k < 16; ++k) {
          const float4 v = *(const float4*)(smem + rpi * 4096 + ((sub + (k << 4)) << 4));
          s.x += v.x; s.y += v.y; s.z += v.z; s.w += v.w;
        }
#pragma unroll
        for (int d = 1; d < 16; d <<= 1) {
          s.x += __shfl_xor(s.x, d, 64);
          s.y += __shfl_xor(s.y, d, 64);
          s.z += __shfl_xor(s.z, d, 64);
          s.w += __shfl_xor(s.w, d, 64);
        }
        if (sub == 0) {
          const int rg = m0 + rhr * 64 + (mt << 5) + (rpi << 1);
          *(float4*)(out + rg * 2) =
              make_float4(fmaxf(s.x + bb3_0, 0.f), fmaxf(s.y + bb3_1, 0.f),
                          fmaxf(s.z + bb3_0, 0.f), fmaxf(s.w + bb3_1, 0.f));
        }
      }
      __syncthreads();
    }
  }
}

extern "C" void kernel_launch(void* const* d_in, const int* in_sizes, int n_in,
                              void* d_out, int out_size, void* d_ws, size_t ws_size,
                              hipStream_t stream) {
  const float* V1 = (const float*)d_in[0];
  const float* V2 = (const float*)d_in[1];
  const float* W1 = (const float*)d_in[2];
  const float* b1 = (const float*)d_in[3];
  const float* W2 = (const float*)d_in[4];
  const float* b2 = (const float*)d_in[5];
  const float* W3 = (const float*)d_in[6];
  const float* b3 = (const float*)d_in[7];

  // ws layout: Ap (1MB f32) | Bp (1MB f32) | W2T (512KB bf16 tiled)
  float* Ap = (float*)d_ws;
  float* Bp = Ap + NROW * HDIM;
  unsigned short* W2T = (unsigned short*)(Bp + NROW * HDIM);

  const int smem_bytes = 131072;  // sA 128KB (epilogue reuses first 64KB)
  (void)hipFuncSetAttribute((const void*)mlp_main,
                            hipFuncAttributeMaxDynamicSharedMemorySize, smem_bytes);

  prep_ab<<<256, 256, 0, stream>>>(V1, V2, W1, b1, Ap, Bp);
  prep_w2<<<128, 256, 0, stream>>>(W2, W2T);
  mlp_main<<<2048, 1024, smem_bytes, stream>>>(Ap, Bp, W2T, b2, W3, b3, (float*)d_out);
}

// Round 15
// 158.867 us; speedup vs baseline: 1.0652x; 1.0652x over previous
//
#include <hip/hip_runtime.h>

// MLPNodeLink: out[i,j] = relu(relu(relu([V1_i|V2_j]@W1+b1)@W2+b2)@W3+b3)
// h1[i,j] = relu(A[i] + B[j]), A=V1@W1[:128]+b1, B=V2@W1[128:]
// Round 15: r13 anchor + WAVE-STAGGERED K-TRAVERSAL. Wave w processes
// k-groups in rotated order starting at w*4 (mod 32) -> waves de-phase, LDS/
// L2/MFMA pipes overlap instead of bursting in lockstep (r9-r14 all summed
// pipes at ~40% each). Sum is k-order-independent; addresses substitute
// s -> (s + w*4) & 31. Everything else identical to r13.

typedef short bf16x8 __attribute__((ext_vector_type(8)));
typedef float f32x16 __attribute__((ext_vector_type(16)));

#define NROW 512
#define FDIM 128
#define HDIM 512

__device__ __forceinline__ unsigned int pk2(float x, float y) {
  unsigned int r;
  asm("v_cvt_pk_bf16_f32 %0, %1, %2" : "=v"(r) : "v"(x), "v"(y));
  return r;
}

// ---- prep_ab: A[i][h] = V1[i]@W1[:128] + b1 ; B[j][h] = V2[j]@W1[128:] ----
__global__ __launch_bounds__(256) void prep_ab(
    const float* __restrict__ V1, const float* __restrict__ V2,
    const float* __restrict__ W1, const float* __restrict__ b1,
    float* __restrict__ Ap, float* __restrict__ Bp) {
  __shared__ float sv[4 * FDIM];
  const int b = blockIdx.x;
  const int t = threadIdx.x;
  const bool isB = b >= 128;
  const int r0 = (b & 127) * 4;
  const float* V = isB ? V2 : V1;
  const float* W = W1 + (isB ? FDIM * HDIM : 0);
  for (int idx = t; idx < 4 * FDIM; idx += 256) sv[idx] = V[r0 * FDIM + idx];
  __syncthreads();
  float s[4][2] = {};
  for (int k = 0; k < FDIM; ++k) {
    const float w0 = W[k * HDIM + t];
    const float w1 = W[k * HDIM + t + 256];
#pragma unroll
    for (int r = 0; r < 4; ++r) {
      const float v = sv[r * FDIM + k];
      s[r][0] += v * w0;
      s[r][1] += v * w1;
    }
  }
  float* O = isB ? Bp : Ap;
  const float bb0 = isB ? 0.f : b1[t];
  const float bb1 = isB ? 0.f : b1[t + 256];
#pragma unroll
  for (int r = 0; r < 4; ++r) {
    O[(r0 + r) * HDIM + t] = s[r][0] + bb0;
    O[(r0 + r) * HDIM + t + 256] = s[r][1] + bb1;
  }
}

// ---- prep_w2: bf16 W2^T as [kc=k/8 (64)][n (512)] 16B chunks ----
__global__ __launch_bounds__(256) void prep_w2(const float* __restrict__ W2,
                                               unsigned short* __restrict__ W2T) {
  const int o = blockIdx.x * 256 + threadIdx.x;  // 128*256 = 32768 chunks
  const int kc = o >> 9;
  const int n = o & 511;
  unsigned int u[4];
#pragma unroll
  for (int e2 = 0; e2 < 4; ++e2)
    u[e2] = pk2(W2[(kc * 8 + 2 * e2) * HDIM + n], W2[(kc * 8 + 2 * e2 + 1) * HDIM + n]);
  *(uint4*)(W2T + (size_t)o * 8) = make_uint4(u[0], u[1], u[2], u[3]);
}

// ---- main: 64 pair-rows x 512 cols per block; 8 waves, wave = 64x64 tile
// as 2x2 frags of 32x32. K: 32 steps of 16, wave-rotated start (w*4);
// af dbuf 1-deep, bfr 3-slot distance-2.
__global__ __launch_bounds__(512, 4) void mlp_main(
    const float* __restrict__ Ap, const float* __restrict__ Bp,
    const unsigned short* __restrict__ W2T, const float* __restrict__ b2,
    const float* __restrict__ W3, const float* __restrict__ b3,
    float* __restrict__ out) {
  extern __shared__ char smem[];
  char* sA = smem;  // 64 KB; epilogue reuses as [16 rowpair][256 slot][16B]

  const int tid = threadIdx.x;
  const int wave = tid >> 6;
  const int lane = tid & 63;
  const int cl = lane & 31;   // frag row/col index
  const int hi = lane >> 5;   // k-octet select
  const int r15 = lane & 15;  // row&15 for this lane's af rows (both mt)
  const int w4 = wave << 2;   // per-wave k-phase stagger

  const int m0 = blockIdx.x * 64;
  const int i = m0 >> 9;
  const int j0 = m0 & 511;

  // ---- fill: h1 tile (64 rows x 512 k) -> sA, 4-bit XOR swizzle ----
  {
    const int c = tid & 63;     // 16B chunk (8 k-elems)
    const int rsub = tid >> 6;  // 0..7
    const float4 a0 = *(const float4*)(Ap + i * HDIM + c * 8);
    const float4 a1 = *(const float4*)(Ap + i * HDIM + c * 8 + 4);
#pragma unroll
    for (int it = 0; it < 8; ++it) {
      const int row = it * 8 + rsub;
      const float4 g0 = *(const float4*)(Bp + (size_t)(j0 + row) * HDIM + c * 8);
      const float4 g1 = *(const float4*)(Bp + (size_t)(j0 + row) * HDIM + c * 8 + 4);
      const uint4 v = make_uint4(
          pk2(fmaxf(a0.x + g0.x, 0.f), fmaxf(a0.y + g0.y, 0.f)),
          pk2(fmaxf(a0.z + g0.z, 0.f), fmaxf(a0.w + g0.w, 0.f)),
          pk2(fmaxf(a1.x + g1.x, 0.f), fmaxf(a1.y + g1.y, 0.f)),
          pk2(fmaxf(a1.z + g1.z, 0.f), fmaxf(a1.w + g1.w, 0.f)));
      *(uint4*)(sA + row * 1024 + ((c ^ (row & 15)) << 4)) = v;
    }
  }

  // hoisted epilogue weights (latency hidden under K-loop)
  float w30[2], w31[2], bb[2];
#pragma unroll
  for (int nt = 0; nt < 2; ++nt) {
    const int n = (wave << 6) + (nt << 5) + cl;
    w30[nt] = W3[2 * n];
    w31[nt] = W3[2 * n + 1];
    bb[nt] = b2[n];
  }
  const float bb3_0 = b3[0], bb3_1 = b3[1];

  __syncthreads();

  // ---- pipelined K-loop (wave-rotated): order-pos s -> k-group (w4+s)&31
  f32x16 acc[2][2];
#pragma unroll
  for (int mt = 0; mt < 2; ++mt)
#pragma unroll
    for (int nt = 0; nt < 2; ++nt)
#pragma unroll
      for (int q = 0; q < 16; ++q) acc[mt][nt][q] = 0.f;

  const char* abase0 = sA + cl * 1024;  // mt=1 at +32768
  const char* bbase = (const char*)W2T + (((wave << 6) + cl) << 4) + (hi << 13);

  bf16x8 af[2][2], bfr[3][2];
  {
    const int g0 = w4 & 31;  // order-pos 0
    const int off = (((g0 << 1) | hi) ^ r15) << 4;
    af[0][0] = *(const bf16x8*)(abase0 + off);
    af[0][1] = *(const bf16x8*)(abase0 + 32768 + off);
#pragma unroll
    for (int q = 0; q < 2; ++q) {  // order-pos 0,1 -> slots 0,1
      const int g = (w4 + q) & 31;
      const char* bp = bbase + ((size_t)g << 14);
      bfr[q][0] = *(const bf16x8*)(bp);
      bfr[q][1] = *(const bf16x8*)(bp + (1 << 9));
    }
  }
#pragma unroll
  for (int s = 0; s < 32; ++s) {
    const int cur = s & 1;
    const int nxt = cur ^ 1;
    // bfr prefetch distance 2 into slot (s+2)%3
    if (s < 30) {
      const int g = (w4 + s + 2) & 31;
      const char* bp = bbase + ((size_t)g << 14);
      bfr[(s + 2) % 3][0] = *(const bf16x8*)(bp);
      bfr[(s + 2) % 3][1] = *(const bf16x8*)(bp + (1 << 9));
    }
    // af prefetch order-pos s+1
    if (s < 31) {
      const int g = (w4 + s + 1) & 31;
      const int off = (((g << 1) | hi) ^ r15) << 4;
      af[nxt][0] = *(const bf16x8*)(abase0 + off);
      af[nxt][1] = *(const bf16x8*)(abase0 + 32768 + off);
    }
    __builtin_amdgcn_s_setprio(1);
#pragma unroll
    for (int nt = 0; nt < 2; ++nt)
#pragma unroll
      for (int mt = 0; mt < 2; ++mt)
        acc[mt][nt] = __builtin_amdgcn_mfma_f32_32x32x16_bf16(af[cur][mt], bfr[s % 3][nt],
                                                              acc[mt][nt], 0, 0, 0);
    __builtin_amdgcn_s_setprio(0);
  }

  __syncthreads();  // sA reads done; buffer reused below

  // ---- epilogue: h2=relu(acc+b2); p=(h2 row-slice)@W3; LDS reduce ----
  for (int mt = 0; mt < 2; ++mt) {
#pragma unroll
    for (int rp = 0; rp < 8; ++rp) {
      const int ra = 2 * rp;  // regs ra, ra+1 -> adjacent rows
      const float h0a = fmaxf(acc[mt][0][ra] + bb[0], 0.f);
      const float h1a = fmaxf(acc[mt][1][ra] + bb[1], 0.f);
      const float h0b = fmaxf(acc[mt][0][ra + 1] + bb[0], 0.f);
      const float h1b = fmaxf(acc[mt][1][ra + 1] + bb[1], 0.f);
      const float4 v = make_float4(h0a * w30[0] + h1a * w30[1], h0a * w31[0] + h1a * w31[1],
                                   h0b * w30[0] + h1b * w30[1], h0b * w31[0] + h1b * w31[1]);
      const int rpi = ((ra & 3) + 8 * (ra >> 2) + 4 * hi) >> 1;
      *(float4*)(smem + rpi * 4096 + (((wave << 5) + cl) << 4)) = v;
    }
    __syncthreads();
    if (tid < 256) {
      const int rpi = tid >> 4;   // 0..15
      const int sub = tid & 15;   // 16 threads per rowpair
      float4 s = make_float4(0.f, 0.f, 0.f, 0.f);
#pragma unroll
      for (int k = 0; k < 16; ++k) {
        const float4 v = *(const float4*)(smem + rpi * 4096 + ((sub + (k << 4)) << 4));
        s.x += v.x; s.y += v.y; s.z += v.z; s.w += v.w;
      }
#pragma unroll
      for (int d = 1; d < 16; d <<= 1) {
        s.x += __shfl_xor(s.x, d, 64);
        s.y += __shfl_xor(s.y, d, 64);
        s.z += __shfl_xor(s.z, d, 64);
        s.w += __shfl_xor(s.w, d, 64);
      }
      if (sub == 0) {
        const int rg = m0 + (mt << 5) + (rpi << 1);
        *(float4*)(out + rg * 2) =
            make_float4(fmaxf(s.x + bb3_0, 0.f), fmaxf(s.y + bb3_1, 0.f),
                        fmaxf(s.z + bb3_0, 0.f), fmaxf(s.w + bb3_1, 0.f));
      }
    }
    __syncthreads();
  }
}

extern "C" void kernel_launch(void* const* d_in, const int* in_sizes, int n_in,
                              void* d_out, int out_size, void* d_ws, size_t ws_size,
                              hipStream_t stream) {
  const float* V1 = (const float*)d_in[0];
  const float* V2 = (const float*)d_in[1];
  const float* W1 = (const float*)d_in[2];
  const float* b1 = (const float*)d_in[3];
  const float* W2 = (const float*)d_in[4];
  const float* b2 = (const float*)d_in[5];
  const float* W3 = (const float*)d_in[6];
  const float* b3 = (const float*)d_in[7];

  // ws layout: Ap (1MB f32) | Bp (1MB f32) | W2T (512KB bf16 tiled)
  float* Ap = (float*)d_ws;
  float* Bp = Ap + NROW * HDIM;
  unsigned short* W2T = (unsigned short*)(Bp + NROW * HDIM);

  const int smem_bytes = 65536;
  (void)hipFuncSetAttribute((const void*)mlp_main,
                            hipFuncAttributeMaxDynamicSharedMemorySize, smem_bytes);

  prep_ab<<<256, 256, 0, stream>>>(V1, V2, W1, b1, Ap, Bp);
  prep_w2<<<128, 256, 0, stream>>>(W2, W2T);
  mlp_main<<<4096, 512, smem_bytes, stream>>>(Ap, Bp, W2T, b2, W3, b3, (float*)d_out);
}

// Round 16
// 149.124 us; speedup vs baseline: 1.1348x; 1.0653x over previous
//
#include <hip/hip_runtime.h>

// MLPNodeLink: out[i,j] = relu(relu(relu([V1_i|V2_j]@W1+b1)@W2+b2)@W3+b3)
// h1[i,j] = relu(A[i] + B[j]), A=V1@W1[:128]+b1, B=V2@W1[128:]
// Round 16: r10 base (BM=128, wave=128x64 via 4mt x 2nt, 1 block/CU,
// 2 waves/SIMD, regs free to 256) + bfr ring 5 (dist-4, covers L2 tail
// latency ~900cy) + prologue loads hoisted before fill + epilogue in 2
// rounds (4 barriers, both 64KB sA halves, 512-thread reduce).

typedef short bf16x8 __attribute__((ext_vector_type(8)));
typedef float f32x16 __attribute__((ext_vector_type(16)));

#define NROW 512
#define FDIM 128
#define HDIM 512

__device__ __forceinline__ unsigned int pk2(float x, float y) {
  unsigned int r;
  asm("v_cvt_pk_bf16_f32 %0, %1, %2" : "=v"(r) : "v"(x), "v"(y));
  return r;
}

// ---- prep_ab: A[i][h] = V1[i]@W1[:128] + b1 ; B[j][h] = V2[j]@W1[128:] ----
__global__ __launch_bounds__(256) void prep_ab(
    const float* __restrict__ V1, const float* __restrict__ V2,
    const float* __restrict__ W1, const float* __restrict__ b1,
    float* __restrict__ Ap, float* __restrict__ Bp) {
  __shared__ float sv[4 * FDIM];
  const int b = blockIdx.x;
  const int t = threadIdx.x;
  const bool isB = b >= 128;
  const int r0 = (b & 127) * 4;
  const float* V = isB ? V2 : V1;
  const float* W = W1 + (isB ? FDIM * HDIM : 0);
  for (int idx = t; idx < 4 * FDIM; idx += 256) sv[idx] = V[r0 * FDIM + idx];
  __syncthreads();
  float s[4][2] = {};
  for (int k = 0; k < FDIM; ++k) {
    const float w0 = W[k * HDIM + t];
    const float w1 = W[k * HDIM + t + 256];
#pragma unroll
    for (int r = 0; r < 4; ++r) {
      const float v = sv[r * FDIM + k];
      s[r][0] += v * w0;
      s[r][1] += v * w1;
    }
  }
  float* O = isB ? Bp : Ap;
  const float bb0 = isB ? 0.f : b1[t];
  const float bb1 = isB ? 0.f : b1[t + 256];
#pragma unroll
  for (int r = 0; r < 4; ++r) {
    O[(r0 + r) * HDIM + t] = s[r][0] + bb0;
    O[(r0 + r) * HDIM + t + 256] = s[r][1] + bb1;
  }
}

// ---- prep_w2: bf16 W2^T as [kc=k/8 (64)][n (512)] 16B chunks ----
__global__ __launch_bounds__(256) void prep_w2(const float* __restrict__ W2,
                                               unsigned short* __restrict__ W2T) {
  const int o = blockIdx.x * 256 + threadIdx.x;  // 128*256 = 32768 chunks
  const int kc = o >> 9;
  const int n = o & 511;
  unsigned int u[4];
#pragma unroll
  for (int e2 = 0; e2 < 4; ++e2)
    u[e2] = pk2(W2[(kc * 8 + 2 * e2) * HDIM + n], W2[(kc * 8 + 2 * e2 + 1) * HDIM + n]);
  *(uint4*)(W2T + (size_t)o * 8) = make_uint4(u[0], u[1], u[2], u[3]);
}

// ---- main: 128 pair-rows x 512 cols per block; 8 waves; wave = 128x64 tile
// as 4 mt x 2 nt frags of 32x32. K: 32 steps of 16; af 1-deep, bfr dist-4.
__global__ __launch_bounds__(512, 2) void mlp_main(
    const float* __restrict__ Ap, const float* __restrict__ Bp,
    const unsigned short* __restrict__ W2T, const float* __restrict__ b2,
    const float* __restrict__ W3, const float* __restrict__ b3,
    float* __restrict__ out) {
  extern __shared__ char smem[];
  char* sA = smem;  // 128 rows * 1024B = 128KB; epilogue reuses both halves

  const int tid = threadIdx.x;
  const int wave = tid >> 6;
  const int lane = tid & 63;
  const int cl = lane & 31;   // frag row/col index
  const int hi = lane >> 5;   // k-octet select
  const int r15 = lane & 15;  // row&15 for af rows (all mt: (mt*32+cl)&15 = cl&15)

  const int m0 = blockIdx.x * 128;
  const int i = m0 >> 9;
  const int j0 = m0 & 511;

  const char* bbase = (const char*)W2T + (((wave << 6) + cl) << 4) + (hi << 13);

  // bfr prologue (issued BEFORE fill so L2 latency hides under fill VALU)
  bf16x8 af[2][4], bfr[5][2];
#pragma unroll
  for (int q = 0; q < 4; ++q) {
    const char* bp = bbase + ((size_t)q << 14);
    bfr[q][0] = *(const bf16x8*)(bp);
    bfr[q][1] = *(const bf16x8*)(bp + (1 << 9));
  }
  // hoisted epilogue weights
  float w30[2], w31[2], bb[2];
#pragma unroll
  for (int nt = 0; nt < 2; ++nt) {
    const int n = (wave << 6) + (nt << 5) + cl;
    w30[nt] = W3[2 * n];
    w31[nt] = W3[2 * n + 1];
    bb[nt] = b2[n];
  }
  const float bb3_0 = b3[0], bb3_1 = b3[1];

  // ---- fill: h1 tile (128 rows x 512 k) -> sA, 4-bit XOR swizzle ----
  {
    const int c = tid & 63;     // 16B chunk (8 k-elems)
    const int rsub = tid >> 6;  // 0..7
    const float4 a0 = *(const float4*)(Ap + i * HDIM + c * 8);
    const float4 a1 = *(const float4*)(Ap + i * HDIM + c * 8 + 4);
#pragma unroll
    for (int it = 0; it < 16; ++it) {
      const int row = it * 8 + rsub;
      const float4 g0 = *(const float4*)(Bp + (size_t)(j0 + row) * HDIM + c * 8);
      const float4 g1 = *(const float4*)(Bp + (size_t)(j0 + row) * HDIM + c * 8 + 4);
      const uint4 v = make_uint4(
          pk2(fmaxf(a0.x + g0.x, 0.f), fmaxf(a0.y + g0.y, 0.f)),
          pk2(fmaxf(a0.z + g0.z, 0.f), fmaxf(a0.w + g0.w, 0.f)),
          pk2(fmaxf(a1.x + g1.x, 0.f), fmaxf(a1.y + g1.y, 0.f)),
          pk2(fmaxf(a1.z + g1.z, 0.f), fmaxf(a1.w + g1.w, 0.f)));
      *(uint4*)(sA + row * 1024 + ((c ^ (row & 15)) << 4)) = v;
    }
  }
  __syncthreads();

  // ---- pipelined K-loop: af from sA (1-deep), bfr from L2 (ring 5, dist-4)
  f32x16 acc[4][2];
#pragma unroll
  for (int mt = 0; mt < 4; ++mt)
#pragma unroll
    for (int nt = 0; nt < 2; ++nt)
#pragma unroll
      for (int q = 0; q < 16; ++q) acc[mt][nt][q] = 0.f;

  const char* abase0 = sA + cl * 1024;  // mt at +mt*32768
  {
    const int off = (hi ^ r15) << 4;  // s=0
#pragma unroll
    for (int mt = 0; mt < 4; ++mt) af[0][mt] = *(const bf16x8*)(abase0 + mt * 32768 + off);
  }
#pragma unroll
  for (int s = 0; s < 32; ++s) {
    const int cur = s & 1;
    if (s < 31) {
      const int off = ((((s + 1) << 1) | hi) ^ r15) << 4;
#pragma unroll
      for (int mt = 0; mt < 4; ++mt)
        af[cur ^ 1][mt] = *(const bf16x8*)(abase0 + mt * 32768 + off);
    }
    if (s < 28) {
      const char* bp = bbase + ((size_t)(s + 4) << 14);
      bfr[(s + 4) % 5][0] = *(const bf16x8*)(bp);
      bfr[(s + 4) % 5][1] = *(const bf16x8*)(bp + (1 << 9));
    }
    __builtin_amdgcn_s_setprio(1);
#pragma unroll
    for (int nt = 0; nt < 2; ++nt)
#pragma unroll
      for (int mt = 0; mt < 4; ++mt)
        acc[mt][nt] = __builtin_amdgcn_mfma_f32_32x32x16_bf16(af[cur][mt], bfr[s % 5][nt],
                                                              acc[mt][nt], 0, 0, 0);
    __builtin_amdgcn_s_setprio(0);
  }

  __syncthreads();  // sA reads done; both 64KB halves reused below

  // ---- epilogue: 2 rounds; round r handles mt = 2r, 2r+1 in parallel ----
#pragma unroll
  for (int rnd = 0; rnd < 2; ++rnd) {
#pragma unroll
    for (int ml = 0; ml < 2; ++ml) {
      const int mt = rnd * 2 + ml;
      char* ebuf = smem + ml * 65536;  // [16 rp][256 slot][16B]
#pragma unroll
      for (int rp = 0; rp < 8; ++rp) {
        const int ra = 2 * rp;
        const float h0a = fmaxf(acc[mt][0][ra] + bb[0], 0.f);
        const float h1a = fmaxf(acc[mt][1][ra] + bb[1], 0.f);
        const float h0b = fmaxf(acc[mt][0][ra + 1] + bb[0], 0.f);
        const float h1b = fmaxf(acc[mt][1][ra + 1] + bb[1], 0.f);
        const float4 v =
            make_float4(h0a * w30[0] + h1a * w30[1], h0a * w31[0] + h1a * w31[1],
                        h0b * w30[0] + h1b * w30[1], h0b * w31[0] + h1b * w31[1]);
        const int rpi = ((ra & 3) + 8 * (ra >> 2) + 4 * hi) >> 1;
        *(float4*)(ebuf + rpi * 4096 + (((wave << 5) + cl) << 4)) = v;
      }
    }
    __syncthreads();
    {
      const int ml = tid >> 8;  // 0/1 -> which mt of this round
      const int t2 = tid & 255;
      const int rpi = t2 >> 4;  // 0..15
      const int sub = t2 & 15;  // 16 threads per rowpair
      const char* ebuf = smem + ml * 65536;
      float4 s4 = make_float4(0.f, 0.f, 0.f, 0.f);
#pragma unroll
      for (int k = 0; k < 16; ++k) {
        const float4 v = *(const float4*)(ebuf + rpi * 4096 + ((sub + (k << 4)) << 4));
        s4.x += v.x; s4.y += v.y; s4.z += v.z; s4.w += v.w;
      }
#pragma unroll
      for (int d = 1; d < 16; d <<= 1) {
        s4.x += __shfl_xor(s4.x, d, 64);
        s4.y += __shfl_xor(s4.y, d, 64);
        s4.z += __shfl_xor(s4.z, d, 64);
        s4.w += __shfl_xor(s4.w, d, 64);
      }
      if (sub == 0) {
        const int rg = m0 + ((rnd * 2 + ml) << 5) + (rpi << 1);
        *(float4*)(out + rg * 2) =
            make_float4(fmaxf(s4.x + bb3_0, 0.f), fmaxf(s4.y + bb3_1, 0.f),
                        fmaxf(s4.z + bb3_0, 0.f), fmaxf(s4.w + bb3_1, 0.f));
      }
    }
    __syncthreads();
  }
}

extern "C" void kernel_launch(void* const* d_in, const int* in_sizes, int n_in,
                              void* d_out, int out_size, void* d_ws, size_t ws_size,
                              hipStream_t stream) {
  const float* V1 = (const float*)d_in[0];
  const float* V2 = (const float*)d_in[1];
  const float* W1 = (const float*)d_in[2];
  const float* b1 = (const float*)d_in[3];
  const float* W2 = (const float*)d_in[4];
  const float* b2 = (const float*)d_in[5];
  const float* W3 = (const float*)d_in[6];
  const float* b3 = (const float*)d_in[7];

  // ws layout: Ap (1MB f32) | Bp (1MB f32) | W2T (512KB bf16 tiled)
  float* Ap = (float*)d_ws;
  float* Bp = Ap + NROW * HDIM;
  unsigned short* W2T = (unsigned short*)(Bp + NROW * HDIM);

  const int smem_bytes = 131072;
  (void)hipFuncSetAttribute((const void*)mlp_main,
                            hipFuncAttributeMaxDynamicSharedMemorySize, smem_bytes);

  prep_ab<<<256, 256, 0, stream>>>(V1, V2, W1, b1, Ap, Bp);
  prep_w2<<<128, 256, 0, stream>>>(W2, W2T);
  mlp_main<<<2048, 512, smem_bytes, stream>>>(Ap, Bp, W2T, b2, W3, b3, (float*)d_out);
}